// Round 20
// baseline (1875.550 us; speedup 1.0000x reference)
//
#include <hip/hip_runtime.h>

// ---------------------------------------------------------------------------
// 2-layer GRU, T=512, B=64, I=H=512, fp32 in/out. Persistent cooperative
// kernel, 256 WGs x 512 thr. Round 20 = r19 with DEVICE-scope (sc1) instead
// of SYSTEM-scope (sc0 sc1) coherent accesses. SC[1:0]: 2=device (MALL is
// the coherence point, shared across XCDs), 3=system (bypasses MALL to HBM).
// r19's FETCH_SIZE=922MB showed polls were paying HBM round trips (~900cyc);
// device scope makes them L3 round trips (~250cyc). NO other changes.
//   G0 (bid 64-95):  gx1[t] = x[t]@W_ih1+b  (static input, free-running)
//   GA (bid  0-31):  h1[t]  = GRU(gx1[t], h1[t-1]@W_hh1+b)
//   GB (bid 96-127): gx2[t] = h1[t]@W_ih2+b
//   GC (bid 32-63):  h2[t]  = GRU(gx2[t], h2[t-1]@W_hh2+b) -> out
// Sync: data-as-flag (tagged fp16 h-rings; gen-tagged fp32 gx rings depth
// 16; producer guard on consumer h-ring slab t-14); issue-early/check-late
// prefetch of gx + guard loads.
// ---------------------------------------------------------------------------

typedef float f32x4 __attribute__((ext_vector_type(4)));
typedef short s16x8 __attribute__((ext_vector_type(8)));
typedef _Float16 f16x8 __attribute__((ext_vector_type(8)));
typedef unsigned u32x2 __attribute__((ext_vector_type(2)));
typedef unsigned u32x4 __attribute__((ext_vector_type(4)));

#define GB_T 512
#define NWG 256
#define NTHR 512
#define SLAB 32768  // halfwords per fp16 h-slab (64 KB)
#define TAG 0x00010001u
#define GXSLAB 98304  // floats per gx slab (64*1536)
#define GXDEPTH 16

// float-word offsets inside ws
#define OFF_PF 0  // 256 u16 prologue flags
#define OFF_RING1 1024
#define OFF_RING2 (OFF_RING1 + 513 * (SLAB / 2))
#define OFF_GX1 (OFF_RING2 + 513 * (SLAB / 2))
#define OFF_GX2 (OFF_GX1 + GXDEPTH * GXSLAB)
// total ~= 80 MB

// ---- device-scope (MALL coherence point) access helpers -------------------
__device__ __forceinline__ void st_dev_u16(unsigned short* p, unsigned v) {
  asm volatile("global_store_short %0, %1, off sc1" ::"v"(p), "v"(v)
               : "memory");
}
__device__ __forceinline__ void st_dev_u32(unsigned* p, unsigned v) {
  asm volatile("global_store_dword %0, %1, off sc1" ::"v"(p), "v"(v)
               : "memory");
}
__device__ __forceinline__ void st_dev_u32x2(unsigned* p, u32x2 v) {
  asm volatile("global_store_dwordx2 %0, %1, off sc1" ::"v"(p), "v"(v)
               : "memory");
}
__device__ __forceinline__ void st_dev_u32x4(unsigned* p, u32x4 v) {
  asm volatile("global_store_dwordx4 %0, %1, off sc1" ::"v"(p), "v"(v)
               : "memory");
}
#define LD_DEV_X4(dst, addr)                          \
  asm volatile("global_load_dwordx4 %0, %1, off sc1" \
               : "=v"(dst)                            \
               : "v"(addr))
#define LD_DEV_X2(dst, addr)                          \
  asm volatile("global_load_dwordx2 %0, %1, off sc1" \
               : "=v"(dst)                            \
               : "v"(addr))
#define LD_DEV_U32(dst, addr)                        \
  asm volatile("global_load_dword %0, %1, off sc1" \
               : "=v"(dst)                           \
               : "v"(addr))

__device__ __forceinline__ unsigned short h16(float f) {
  return __builtin_bit_cast(unsigned short, (_Float16)f);
}
__device__ __forceinline__ unsigned packh2t(float a, float b) {
  return ((unsigned)h16(a) | ((unsigned)h16(b) << 16)) | TAG;
}

// prologue barrier poll: lanes 0..31 each watch 8 u16 flags (256 total)
__device__ __forceinline__ void poll_pf(const unsigned* fbase, unsigned tgt) {
  const int lane = threadIdx.x & 63;
  const bool mine = lane < 32;
  const unsigned* fp = fbase + lane * 4;
  for (;;) {
    int ok = 1;
    if (mine) {
      u32x4 f;
      LD_DEV_X4(f, fp);
      asm volatile("s_waitcnt vmcnt(0)" ::: "memory");
      ok = ((f.x & 0xFFFFu) >= tgt) & ((f.x >> 16) >= tgt) &
           ((f.y & 0xFFFFu) >= tgt) & ((f.y >> 16) >= tgt) &
           ((f.z & 0xFFFFu) >= tgt) & ((f.z >> 16) >= tgt) &
           ((f.w & 0xFFFFu) >= tgt) & ((f.w >> 16) >= tgt);
    }
    if (__all(ok)) break;
    __builtin_amdgcn_s_sleep(1);
  }
}

// poll-load 8 tagged A-granules (wave's K=64 slice) into MFMA regs
__device__ __forceinline__ void poll_a8(const char* slab, int w, int lg,
                                        int l15, u32x4* q) {
  const char* base = slab + lg * 1024 + l15 * 16;
  for (;;) {
#pragma unroll
    for (int i = 0; i < 8; ++i) {
      const int kcl = w * 2 + (i >> 2);
      const int m = i & 3;
      LD_DEV_X4(q[i], (const unsigned*)(base + kcl * 4096 + m * 256));
    }
    asm volatile("s_waitcnt vmcnt(0)" ::: "memory");
    unsigned v = 0xFFFFFFFFu;
#pragma unroll
    for (int i = 0; i < 8; ++i) v &= q[i].x & q[i].y & q[i].z & q[i].w;
    if (__all((v & TAG) == TAG)) break;
  }
}

// plain cached load of 8 A-granules (static x-scratch)
__device__ __forceinline__ void load_a8(const char* slab, int w, int lg,
                                        int l15, u32x4* q) {
  const char* base = slab + lg * 1024 + l15 * 16;
#pragma unroll
  for (int i = 0; i < 8; ++i) {
    const int kcl = w * 2 + (i >> 2);
    const int m = i & 3;
    q[i] = *(const u32x4*)(base + kcl * 4096 + m * 256);
  }
}

// fp32 row-major [64][512] slab -> tiled tagged-fp16 slab
// halfword idx = (k>>3)*512 + row*8 + (k&7)   [512 threads]
__device__ __forceinline__ void convert_slab(const float* __restrict__ src,
                                             unsigned short* __restrict__ dst,
                                             int tid) {
  const int row = tid & 63;
  const int kg0 = tid >> 6;
#pragma unroll
  for (int i = 0; i < 8; ++i) {
    const int kg = kg0 + 8 * i;
    const float* s = src + row * 512 + kg * 8;
    f32x4 a = *(const f32x4*)s;
    f32x4 b = *(const f32x4*)(s + 4);
    u32x4 o;
    o.x = packh2t(a.x, a.y);
    o.y = packh2t(a.z, a.w);
    o.z = packh2t(b.x, b.y);
    o.w = packh2t(b.z, b.w);
    st_dev_u32x4((unsigned*)(dst + kg * 512 + row * 8), o);
  }
}

__global__ void gru_init(float* __restrict__ ws) {
  unsigned* p = (unsigned*)ws;
  for (int i = threadIdx.x; i < 1024; i += 256) st_dev_u32(&p[i], 0u);
}

__global__ __launch_bounds__(NTHR, 1) void gru_persist(
    const float* __restrict__ x, const float* __restrict__ h0,
    const float* __restrict__ w_ih, const float* __restrict__ w_hh,
    const float* __restrict__ b_ih, const float* __restrict__ b_hh,
    float* __restrict__ out, float* __restrict__ ws) {
  __shared__ float part[24576];  // 96 tiles x 256 f32 = 96 KB

  const int tid = threadIdx.x;
  const int lane = tid & 63;
  const int wave = __builtin_amdgcn_readfirstlane(tid >> 6);  // 0..7
  const int bid = blockIdx.x;
  const int grp = bid >> 5;  // 0 GA, 1 GC, 2 G0, 3 GB (bid<128)
  const int rank = bid & 31;
  const int j0 = rank << 4;

  unsigned short* pf = (unsigned short*)(ws + OFF_PF);
  unsigned short* ring1 = (unsigned short*)(ws + OFF_RING1);
  unsigned short* ring2 = (unsigned short*)(ws + OFF_RING2);
  float* gx1 = ws + OFF_GX1;
  float* gx2 = ws + OFF_GX2;

  // Drop stale L1/L2 lines (poison / prior replay) before any cached read.
  __builtin_amdgcn_fence(__ATOMIC_ACQUIRE, "agent");
  __syncthreads();

  // ---- prologue 1: zero h-ring slabs 1..512 + both gx rings --------------
  {
    const unsigned bt = (unsigned)bid * 512u + (unsigned)tid;
#pragma unroll
    for (int it = 0; it < 32; ++it) {
      const unsigned gidx = bt * 32u + it;
      const unsigned ring = gidx >> 21;
      const unsigned rem = gidx & 2097151u;
      const unsigned slab = rem >> 12;
      const unsigned gg = rem & 4095u;
      unsigned short* base =
          (ring ? ring2 : ring1) + (size_t)(slab + 1) * SLAB + gg * 8;
      u32x4 z = {0u, 0u, 0u, 0u};
      st_dev_u32x4((unsigned*)base, z);
    }
#pragma unroll
    for (int it = 0; it < 6; ++it) {
      const unsigned g = bt * 6u + it;
      u32x4 z = {0u, 0u, 0u, 0u};
      st_dev_u32x4((unsigned*)(gx1 + (size_t)g * 4), z);
    }
  }

  // ---- prologue 2: x -> tagged fp16 scratch in out[]; h0 -> ring slot 0 --
  for (int i = 0; i < 2; ++i) {
    const int t = bid * 2 + i;
    convert_slab(x + (size_t)t * 32768,
                 (unsigned short*)(out + (size_t)t * 32768), tid);
  }
  if (bid == 0) convert_slab(h0, ring1, tid);
  if (bid == 1) convert_slab(h0 + 32768, ring2, tid);

  // ---- prologue 3 (active WGs): stationary weights + per-thread state ----
  const int l15 = lane & 15, lg = lane >> 4;
  const int eb = tid >> 3;        // batch row 0..63
  const int ejp = (tid & 7) * 2;  // col pair 0..14
  const int em = eb >> 4, erow = eb & 15;
  f16x8 bw[3][2];
  float hprev0 = 0.f, hprev1 = 0.f;
  float bb0[3], bb1[3];  // recur: b_hh ; producer: b_ih
  if (bid < 128) {
    const float* Wm;
    const float* bias;
    if (grp == 0) { Wm = w_hh;                     bias = b_hh; }
    else if (grp == 1) { Wm = w_hh + 1536 * 512;   bias = b_hh + 1536; }
    else if (grp == 2) { Wm = w_ih;                bias = b_ih; }
    else { Wm = w_ih + (size_t)1536 * 512;         bias = b_ih + 1536; }
#pragma unroll
    for (int g = 0; g < 3; ++g)
#pragma unroll
      for (int kc = 0; kc < 2; ++kc) {
        const float* p = Wm + (size_t)(g * 512 + j0 + l15) * 512 + wave * 64 +
                         kc * 32 + lg * 8;
        f16x8 v;
#pragma unroll
        for (int e = 0; e < 8; ++e) v[e] = (_Float16)p[e];
        bw[g][kc] = v;
      }
#pragma unroll
    for (int gg = 0; gg < 3; ++gg) {
      bb0[gg] = bias[gg * 512 + j0 + ejp];
      bb1[gg] = bias[gg * 512 + j0 + ejp + 1];
    }
    if (grp < 2) {
      hprev0 = h0[((size_t)(grp * 64 + eb)) * 512 + j0 + ejp];
      hprev1 = h0[((size_t)(grp * 64 + eb)) * 512 + j0 + ejp + 1];
    }
  }

  // ---- prologue barrier ----
  asm volatile("s_waitcnt vmcnt(0)" ::: "memory");
  __syncthreads();
  if (tid == 0) st_dev_u16(&pf[bid], 1u);
  if (bid >= 128) return;
  poll_pf((const unsigned*)pf, 1u);

  // group-specific pointers
  unsigned short* ringA = (grp == 1) ? ring2 : ring1;  // A-src (GA,GB:r1 GC:r2)
  unsigned short* ringW = (grp == 0) ? ring1 : ring2;  // h-ring written (recur)
  unsigned short* ringG = (grp == 2) ? ring1 : ring2;  // guard ring (producer)
  float* gxr = (grp == 0) ? gx1 : gx2;                 // gx read (recur)
  float* gxw = (grp == 2) ? gx1 : gx2;                 // gx write (producer)

  const int j = j0 + ejp;
  const int toff = (j >> 3) * 512 + eb * 8 + (j & 7);  // halfword idx (even)

  // ======================= main loop: t = 0..511 ==========================
  for (int t = 0; t < GB_T; ++t) {
    const unsigned gen = ((unsigned)(t >> 4) % 3u) + 1u;

    // ---- ISSUE-EARLY: gx loads (recurrence) / guard load (producer) ----
    u32x2 gxv[3];
    unsigned guardv = TAG;
    const float* gb_ = gxr + (size_t)(t & 15) * GXSLAB + eb * 1536 + j;
    const unsigned* ga =
        (const unsigned*)(ringG + (size_t)(t - 14) * SLAB + toff);
    if (grp < 2) {
      LD_DEV_X2(gxv[0], (const unsigned*)gb_);
      LD_DEV_X2(gxv[1], (const unsigned*)(gb_ + 512));
      LD_DEV_X2(gxv[2], (const unsigned*)(gb_ + 1024));
    } else if (t >= 15) {
      LD_DEV_U32(guardv, ga);
    }

    // ---- A-operand: 8 granules into regs ----
    u32x4 q[8];
    if (grp == 2) {
      load_a8((const char*)(out + (size_t)t * 32768), wave, lg, l15, q);
    } else {
      const unsigned short* sl =
          (grp == 3) ? ringA + (size_t)(t + 1) * SLAB   // h1[t]
                     : ringA + (size_t)t * SLAB;        // h[t-1]
      poll_a8((const char*)sl, wave, lg, l15, q);  // vmcnt(0) inside covers
    }                                              // the prefetched loads

    // ---- MFMA: K=64 slice, all 3 gates ----
    f32x4 acc[3][4];
#pragma unroll
    for (int g = 0; g < 3; ++g)
#pragma unroll
      for (int m = 0; m < 4; ++m) acc[g][m] = (f32x4)(0.f);
#pragma unroll
    for (int kc = 0; kc < 2; ++kc)
#pragma unroll
      for (int g = 0; g < 3; ++g) {
        const f16x8 b = bw[g][kc];
#pragma unroll
        for (int m = 0; m < 4; ++m)
          acc[g][m] = __builtin_amdgcn_mfma_f32_16x16x32_f16(
              __builtin_bit_cast(f16x8, q[kc * 4 + m]), b, acc[g][m], 0, 0, 0);
      }
#pragma unroll
    for (int g = 0; g < 3; ++g)
#pragma unroll
      for (int m = 0; m < 4; ++m)
#pragma unroll
        for (int r2 = 0; r2 < 4; ++r2)
          part[(wave * 12 + g * 4 + m) * 256 + (lg * 4 + r2) * 16 + l15] =
              acc[g][m][r2];
    __syncthreads();  // part[] complete

    // ---- epilogue ----
    const int o0 = erow * 16 + ejp;
    float S0[3], S1[3];
#pragma unroll
    for (int gg = 0; gg < 3; ++gg) {
      const int tb = (gg * 4 + em) * 256;
      S0[gg] = part[0 * 3072 + tb + o0] + part[1 * 3072 + tb + o0] +
               part[2 * 3072 + tb + o0] + part[3 * 3072 + tb + o0] +
               part[4 * 3072 + tb + o0] + part[5 * 3072 + tb + o0] +
               part[6 * 3072 + tb + o0] + part[7 * 3072 + tb + o0] + bb0[gg];
      S1[gg] = part[0 * 3072 + tb + o0 + 1] + part[1 * 3072 + tb + o0 + 1] +
               part[2 * 3072 + tb + o0 + 1] + part[3 * 3072 + tb + o0 + 1] +
               part[4 * 3072 + tb + o0 + 1] + part[5 * 3072 + tb + o0 + 1] +
               part[6 * 3072 + tb + o0 + 1] + part[7 * 3072 + tb + o0 + 1] +
               bb1[gg];
    }
    if (grp < 2) {
      // CHECK-LATE: gen check on prefetched gxv; retry path as r17/r19
      for (;;) {
        int ok = ((gxv[0].x & 3u) == gen) & ((gxv[0].y & 3u) == gen) &
                 ((gxv[1].x & 3u) == gen) & ((gxv[1].y & 3u) == gen) &
                 ((gxv[2].x & 3u) == gen) & ((gxv[2].y & 3u) == gen);
        if (__all(ok)) break;
        __builtin_amdgcn_s_sleep(1);
        LD_DEV_X2(gxv[0], (const unsigned*)gb_);
        LD_DEV_X2(gxv[1], (const unsigned*)(gb_ + 512));
        LD_DEV_X2(gxv[2], (const unsigned*)(gb_ + 1024));
        asm volatile("s_waitcnt vmcnt(0)" ::: "memory");
      }
      const float r0 =
          1.f / (1.f + __expf(-(__uint_as_float(gxv[0].x) + S0[0])));
      const float z0 =
          1.f / (1.f + __expf(-(__uint_as_float(gxv[1].x) + S0[1])));
      const float a0 = __uint_as_float(gxv[2].x) + r0 * S0[2];
      const float n0 = 1.f - 2.f / (1.f + __expf(2.f * a0));
      const float hn0 = (1.f - z0) * n0 + z0 * hprev0;
      const float r1 =
          1.f / (1.f + __expf(-(__uint_as_float(gxv[0].y) + S1[0])));
      const float z1 =
          1.f / (1.f + __expf(-(__uint_as_float(gxv[1].y) + S1[1])));
      const float a1 = __uint_as_float(gxv[2].y) + r1 * S1[2];
      const float n1 = 1.f - 2.f / (1.f + __expf(2.f * a1));
      const float hn1 = (1.f - z1) * n1 + z1 * hprev1;
      hprev0 = hn0;
      hprev1 = hn1;
      st_dev_u32((unsigned*)(ringW + (size_t)(t + 1) * SLAB + toff),
                 packh2t(hn0, hn1));
      if (grp == 1) {
        u32x2 fo;
        fo.x = __float_as_uint(hn0);
        fo.y = __float_as_uint(hn1);
        *(u32x2*)(out + (size_t)t * 32768 + eb * 512 + j) = fo;
      }
    } else {
      // CHECK-LATE guard: cover the prefetched load, then verify/retry
      if (t >= 15) {
        asm volatile("s_waitcnt vmcnt(0)" ::: "memory");
        for (;;) {
          if (__all((guardv & TAG) == TAG)) break;
          __builtin_amdgcn_s_sleep(1);
          LD_DEV_U32(guardv, ga);
          asm volatile("s_waitcnt vmcnt(0)" ::: "memory");
        }
      }
      float* gd = gxw + (size_t)(t & 15) * GXSLAB + eb * 1536 + j;
#pragma unroll
      for (int gg = 0; gg < 3; ++gg) {
        u32x2 o;
        o.x = (__float_as_uint(S0[gg]) & ~3u) | gen;
        o.y = (__float_as_uint(S1[gg]) & ~3u) | gen;
        st_dev_u32x2((unsigned*)(gd + gg * 512), o);
      }
    }
    __syncthreads();  // epilogue part-reads done -> next step may overwrite
  }
  asm volatile("s_waitcnt vmcnt(0)" ::: "memory");  // drain final stores
}

extern "C" void kernel_launch(void* const* d_in, const int* in_sizes, int n_in,
                              void* d_out, int out_size, void* d_ws,
                              size_t ws_size, hipStream_t stream) {
  const float* x = (const float*)d_in[0];
  const float* h0 = (const float*)d_in[1];
  const float* w_ih = (const float*)d_in[2];
  const float* w_hh = (const float*)d_in[3];
  const float* b_ih = (const float*)d_in[4];
  const float* b_hh = (const float*)d_in[5];
  float* out = (float*)d_out;
  float* ws = (float*)d_ws;

  gru_init<<<1, 256, 0, stream>>>(ws);

  void* args[] = {(void*)&x,    (void*)&h0,   (void*)&w_ih, (void*)&w_hh,
                  (void*)&b_ih, (void*)&b_hh, (void*)&out,  (void*)&ws};
  (void)hipLaunchCooperativeKernel((const void*)gru_persist, dim3(NWG),
                                   dim3(NTHR), args, 0, stream);
}

// Round 22
// 1870.698 us; speedup vs baseline: 1.0026x; 1.0026x over previous
//
#include <hip/hip_runtime.h>

// ---------------------------------------------------------------------------
// 2-layer GRU, T=512, B=64, I=H=512, fp32 in/out. Persistent cooperative
// kernel, 256 WGs x 512 thr. Round 22 = REVERT to r19 (best passing,
// 1874us). r21's selective-reload poll corrupted kept granules (divergent
// inline-asm "=v" outputs don't guarantee old-value merge for masked-off
// lanes) -> reverted.
//   G0 (bid 64-95):  gx1[t] = x[t]@W_ih1+b  (static input, free-running)
//   GA (bid  0-31):  h1[t]  = GRU(gx1[t], h1[t-1]@W_hh1+b)
//   GB (bid 96-127): gx2[t] = h1[t]@W_ih2+b
//   GC (bid 32-63):  h2[t]  = GRU(gx2[t], h2[t-1]@W_hh2+b) -> out
// Sync: data-as-flag (tagged fp16 h-rings; gen-tagged fp32 gx rings depth
// 16; producer guard on consumer h-ring slab t-14); issue-early/check-late
// prefetch of gx + guard loads.
// ---------------------------------------------------------------------------

typedef float f32x4 __attribute__((ext_vector_type(4)));
typedef short s16x8 __attribute__((ext_vector_type(8)));
typedef _Float16 f16x8 __attribute__((ext_vector_type(8)));
typedef unsigned u32x2 __attribute__((ext_vector_type(2)));
typedef unsigned u32x4 __attribute__((ext_vector_type(4)));

#define GB_T 512
#define NWG 256
#define NTHR 512
#define SLAB 32768  // halfwords per fp16 h-slab (64 KB)
#define TAG 0x00010001u
#define GXSLAB 98304  // floats per gx slab (64*1536)
#define GXDEPTH 16

// float-word offsets inside ws
#define OFF_PF 0  // 256 u16 prologue flags
#define OFF_RING1 1024
#define OFF_RING2 (OFF_RING1 + 513 * (SLAB / 2))
#define OFF_GX1 (OFF_RING2 + 513 * (SLAB / 2))
#define OFF_GX2 (OFF_GX1 + GXDEPTH * GXSLAB)
// total ~= 80 MB

__device__ __forceinline__ void st_l3_u16(unsigned short* p, unsigned v) {
  asm volatile("global_store_short %0, %1, off sc0 sc1" ::"v"(p), "v"(v)
               : "memory");
}
__device__ __forceinline__ void st_l3_u32(unsigned* p, unsigned v) {
  asm volatile("global_store_dword %0, %1, off sc0 sc1" ::"v"(p), "v"(v)
               : "memory");
}
__device__ __forceinline__ void st_l3_u32x2(unsigned* p, u32x2 v) {
  asm volatile("global_store_dwordx2 %0, %1, off sc0 sc1" ::"v"(p), "v"(v)
               : "memory");
}
__device__ __forceinline__ void st_l3_u32x4(unsigned* p, u32x4 v) {
  asm volatile("global_store_dwordx4 %0, %1, off sc0 sc1" ::"v"(p), "v"(v)
               : "memory");
}
#define LD_L3_X4(dst, addr)                               \
  asm volatile("global_load_dwordx4 %0, %1, off sc0 sc1" \
               : "=v"(dst)                                \
               : "v"(addr))
#define LD_L3_X2(dst, addr)                               \
  asm volatile("global_load_dwordx2 %0, %1, off sc0 sc1" \
               : "=v"(dst)                                \
               : "v"(addr))
#define LD_L3_U32(dst, addr)                             \
  asm volatile("global_load_dword %0, %1, off sc0 sc1" \
               : "=v"(dst)                               \
               : "v"(addr))

__device__ __forceinline__ unsigned short h16(float f) {
  return __builtin_bit_cast(unsigned short, (_Float16)f);
}
__device__ __forceinline__ unsigned packh2t(float a, float b) {
  return ((unsigned)h16(a) | ((unsigned)h16(b) << 16)) | TAG;
}

// prologue barrier poll: lanes 0..31 each watch 8 u16 flags (256 total)
__device__ __forceinline__ void poll_pf(const unsigned* fbase, unsigned tgt) {
  const int lane = threadIdx.x & 63;
  const bool mine = lane < 32;
  const unsigned* fp = fbase + lane * 4;
  for (;;) {
    int ok = 1;
    if (mine) {
      u32x4 f;
      LD_L3_X4(f, fp);
      asm volatile("s_waitcnt vmcnt(0)" ::: "memory");
      ok = ((f.x & 0xFFFFu) >= tgt) & ((f.x >> 16) >= tgt) &
           ((f.y & 0xFFFFu) >= tgt) & ((f.y >> 16) >= tgt) &
           ((f.z & 0xFFFFu) >= tgt) & ((f.z >> 16) >= tgt) &
           ((f.w & 0xFFFFu) >= tgt) & ((f.w >> 16) >= tgt);
    }
    if (__all(ok)) break;
    __builtin_amdgcn_s_sleep(1);
  }
}

// poll-load 8 tagged A-granules (wave's K=64 slice) into MFMA regs
__device__ __forceinline__ void poll_a8(const char* slab, int w, int lg,
                                        int l15, u32x4* q) {
  const char* base = slab + lg * 1024 + l15 * 16;
  for (;;) {
#pragma unroll
    for (int i = 0; i < 8; ++i) {
      const int kcl = w * 2 + (i >> 2);
      const int m = i & 3;
      LD_L3_X4(q[i], (const unsigned*)(base + kcl * 4096 + m * 256));
    }
    asm volatile("s_waitcnt vmcnt(0)" ::: "memory");
    unsigned v = 0xFFFFFFFFu;
#pragma unroll
    for (int i = 0; i < 8; ++i) v &= q[i].x & q[i].y & q[i].z & q[i].w;
    if (__all((v & TAG) == TAG)) break;
  }
}

// plain cached load of 8 A-granules (static x-scratch)
__device__ __forceinline__ void load_a8(const char* slab, int w, int lg,
                                        int l15, u32x4* q) {
  const char* base = slab + lg * 1024 + l15 * 16;
#pragma unroll
  for (int i = 0; i < 8; ++i) {
    const int kcl = w * 2 + (i >> 2);
    const int m = i & 3;
    q[i] = *(const u32x4*)(base + kcl * 4096 + m * 256);
  }
}

// fp32 row-major [64][512] slab -> tiled tagged-fp16 slab
// halfword idx = (k>>3)*512 + row*8 + (k&7)   [512 threads]
__device__ __forceinline__ void convert_slab(const float* __restrict__ src,
                                             unsigned short* __restrict__ dst,
                                             int tid) {
  const int row = tid & 63;
  const int kg0 = tid >> 6;
#pragma unroll
  for (int i = 0; i < 8; ++i) {
    const int kg = kg0 + 8 * i;
    const float* s = src + row * 512 + kg * 8;
    f32x4 a = *(const f32x4*)s;
    f32x4 b = *(const f32x4*)(s + 4);
    u32x4 o;
    o.x = packh2t(a.x, a.y);
    o.y = packh2t(a.z, a.w);
    o.z = packh2t(b.x, b.y);
    o.w = packh2t(b.z, b.w);
    st_l3_u32x4((unsigned*)(dst + kg * 512 + row * 8), o);
  }
}

__global__ void gru_init(float* __restrict__ ws) {
  unsigned* p = (unsigned*)ws;
  for (int i = threadIdx.x; i < 1024; i += 256) st_l3_u32(&p[i], 0u);
}

__global__ __launch_bounds__(NTHR, 1) void gru_persist(
    const float* __restrict__ x, const float* __restrict__ h0,
    const float* __restrict__ w_ih, const float* __restrict__ w_hh,
    const float* __restrict__ b_ih, const float* __restrict__ b_hh,
    float* __restrict__ out, float* __restrict__ ws) {
  __shared__ float part[24576];  // 96 tiles x 256 f32 = 96 KB

  const int tid = threadIdx.x;
  const int lane = tid & 63;
  const int wave = __builtin_amdgcn_readfirstlane(tid >> 6);  // 0..7
  const int bid = blockIdx.x;
  const int grp = bid >> 5;  // 0 GA, 1 GC, 2 G0, 3 GB (bid<128)
  const int rank = bid & 31;
  const int j0 = rank << 4;

  unsigned short* pf = (unsigned short*)(ws + OFF_PF);
  unsigned short* ring1 = (unsigned short*)(ws + OFF_RING1);
  unsigned short* ring2 = (unsigned short*)(ws + OFF_RING2);
  float* gx1 = ws + OFF_GX1;
  float* gx2 = ws + OFF_GX2;

  // Drop stale L1/L2 lines (poison / prior replay) before any cached read.
  __builtin_amdgcn_fence(__ATOMIC_ACQUIRE, "agent");
  __syncthreads();

  // ---- prologue 1: zero h-ring slabs 1..512 + both gx rings --------------
  {
    const unsigned bt = (unsigned)bid * 512u + (unsigned)tid;
#pragma unroll
    for (int it = 0; it < 32; ++it) {
      const unsigned gidx = bt * 32u + it;
      const unsigned ring = gidx >> 21;
      const unsigned rem = gidx & 2097151u;
      const unsigned slab = rem >> 12;
      const unsigned gg = rem & 4095u;
      unsigned short* base =
          (ring ? ring2 : ring1) + (size_t)(slab + 1) * SLAB + gg * 8;
      u32x4 z = {0u, 0u, 0u, 0u};
      st_l3_u32x4((unsigned*)base, z);
    }
#pragma unroll
    for (int it = 0; it < 6; ++it) {
      const unsigned g = bt * 6u + it;
      u32x4 z = {0u, 0u, 0u, 0u};
      st_l3_u32x4((unsigned*)(gx1 + (size_t)g * 4), z);
    }
  }

  // ---- prologue 2: x -> tagged fp16 scratch in out[]; h0 -> ring slot 0 --
  for (int i = 0; i < 2; ++i) {
    const int t = bid * 2 + i;
    convert_slab(x + (size_t)t * 32768,
                 (unsigned short*)(out + (size_t)t * 32768), tid);
  }
  if (bid == 0) convert_slab(h0, ring1, tid);
  if (bid == 1) convert_slab(h0 + 32768, ring2, tid);

  // ---- prologue 3 (active WGs): stationary weights + per-thread state ----
  const int l15 = lane & 15, lg = lane >> 4;
  const int eb = tid >> 3;        // batch row 0..63
  const int ejp = (tid & 7) * 2;  // col pair 0..14
  const int em = eb >> 4, erow = eb & 15;
  f16x8 bw[3][2];
  float hprev0 = 0.f, hprev1 = 0.f;
  float bb0[3], bb1[3];  // recur: b_hh ; producer: b_ih
  if (bid < 128) {
    const float* Wm;
    const float* bias;
    if (grp == 0) { Wm = w_hh;                     bias = b_hh; }
    else if (grp == 1) { Wm = w_hh + 1536 * 512;   bias = b_hh + 1536; }
    else if (grp == 2) { Wm = w_ih;                bias = b_ih; }
    else { Wm = w_ih + (size_t)1536 * 512;         bias = b_ih + 1536; }
#pragma unroll
    for (int g = 0; g < 3; ++g)
#pragma unroll
      for (int kc = 0; kc < 2; ++kc) {
        const float* p = Wm + (size_t)(g * 512 + j0 + l15) * 512 + wave * 64 +
                         kc * 32 + lg * 8;
        f16x8 v;
#pragma unroll
        for (int e = 0; e < 8; ++e) v[e] = (_Float16)p[e];
        bw[g][kc] = v;
      }
#pragma unroll
    for (int gg = 0; gg < 3; ++gg) {
      bb0[gg] = bias[gg * 512 + j0 + ejp];
      bb1[gg] = bias[gg * 512 + j0 + ejp + 1];
    }
    if (grp < 2) {
      hprev0 = h0[((size_t)(grp * 64 + eb)) * 512 + j0 + ejp];
      hprev1 = h0[((size_t)(grp * 64 + eb)) * 512 + j0 + ejp + 1];
    }
  }

  // ---- prologue barrier ----
  asm volatile("s_waitcnt vmcnt(0)" ::: "memory");
  __syncthreads();
  if (tid == 0) st_l3_u16(&pf[bid], 1u);
  if (bid >= 128) return;
  poll_pf((const unsigned*)pf, 1u);

  // group-specific pointers
  unsigned short* ringA = (grp == 1) ? ring2 : ring1;  // A-src (GA,GB:r1 GC:r2)
  unsigned short* ringW = (grp == 0) ? ring1 : ring2;  // h-ring written (recur)
  unsigned short* ringG = (grp == 2) ? ring1 : ring2;  // guard ring (producer)
  float* gxr = (grp == 0) ? gx1 : gx2;                 // gx read (recur)
  float* gxw = (grp == 2) ? gx1 : gx2;                 // gx write (producer)

  const int j = j0 + ejp;
  const int toff = (j >> 3) * 512 + eb * 8 + (j & 7);  // halfword idx (even)

  // ======================= main loop: t = 0..511 ==========================
  for (int t = 0; t < GB_T; ++t) {
    const unsigned gen = ((unsigned)(t >> 4) % 3u) + 1u;

    // ---- ISSUE-EARLY: gx loads (recurrence) / guard load (producer) ----
    u32x2 gxv[3];
    unsigned guardv = TAG;
    const float* gb_ = gxr + (size_t)(t & 15) * GXSLAB + eb * 1536 + j;
    const unsigned* ga =
        (const unsigned*)(ringG + (size_t)(t - 14) * SLAB + toff);
    if (grp < 2) {
      LD_L3_X2(gxv[0], (const unsigned*)gb_);
      LD_L3_X2(gxv[1], (const unsigned*)(gb_ + 512));
      LD_L3_X2(gxv[2], (const unsigned*)(gb_ + 1024));
    } else if (t >= 15) {
      LD_L3_U32(guardv, ga);
    }

    // ---- A-operand: 8 granules into regs ----
    u32x4 q[8];
    if (grp == 2) {
      load_a8((const char*)(out + (size_t)t * 32768), wave, lg, l15, q);
    } else {
      const unsigned short* sl =
          (grp == 3) ? ringA + (size_t)(t + 1) * SLAB   // h1[t]
                     : ringA + (size_t)t * SLAB;        // h[t-1]
      poll_a8((const char*)sl, wave, lg, l15, q);  // vmcnt(0) inside covers
    }                                              // the prefetched loads

    // ---- MFMA: K=64 slice, all 3 gates ----
    f32x4 acc[3][4];
#pragma unroll
    for (int g = 0; g < 3; ++g)
#pragma unroll
      for (int m = 0; m < 4; ++m) acc[g][m] = (f32x4)(0.f);
#pragma unroll
    for (int kc = 0; kc < 2; ++kc)
#pragma unroll
      for (int g = 0; g < 3; ++g) {
        const f16x8 b = bw[g][kc];
#pragma unroll
        for (int m = 0; m < 4; ++m)
          acc[g][m] = __builtin_amdgcn_mfma_f32_16x16x32_f16(
              __builtin_bit_cast(f16x8, q[kc * 4 + m]), b, acc[g][m], 0, 0, 0);
      }
#pragma unroll
    for (int g = 0; g < 3; ++g)
#pragma unroll
      for (int m = 0; m < 4; ++m)
#pragma unroll
        for (int r2 = 0; r2 < 4; ++r2)
          part[(wave * 12 + g * 4 + m) * 256 + (lg * 4 + r2) * 16 + l15] =
              acc[g][m][r2];
    __syncthreads();  // part[] complete

    // ---- epilogue ----
    const int o0 = erow * 16 + ejp;
    float S0[3], S1[3];
#pragma unroll
    for (int gg = 0; gg < 3; ++gg) {
      const int tb = (gg * 4 + em) * 256;
      S0[gg] = part[0 * 3072 + tb + o0] + part[1 * 3072 + tb + o0] +
               part[2 * 3072 + tb + o0] + part[3 * 3072 + tb + o0] +
               part[4 * 3072 + tb + o0] + part[5 * 3072 + tb + o0] +
               part[6 * 3072 + tb + o0] + part[7 * 3072 + tb + o0] + bb0[gg];
      S1[gg] = part[0 * 3072 + tb + o0 + 1] + part[1 * 3072 + tb + o0 + 1] +
               part[2 * 3072 + tb + o0 + 1] + part[3 * 3072 + tb + o0 + 1] +
               part[4 * 3072 + tb + o0 + 1] + part[5 * 3072 + tb + o0 + 1] +
               part[6 * 3072 + tb + o0 + 1] + part[7 * 3072 + tb + o0 + 1] +
               bb1[gg];
    }
    if (grp < 2) {
      // CHECK-LATE: gen check on prefetched gxv; retry path identical to r17
      for (;;) {
        int ok = ((gxv[0].x & 3u) == gen) & ((gxv[0].y & 3u) == gen) &
                 ((gxv[1].x & 3u) == gen) & ((gxv[1].y & 3u) == gen) &
                 ((gxv[2].x & 3u) == gen) & ((gxv[2].y & 3u) == gen);
        if (__all(ok)) break;
        __builtin_amdgcn_s_sleep(1);
        LD_L3_X2(gxv[0], (const unsigned*)gb_);
        LD_L3_X2(gxv[1], (const unsigned*)(gb_ + 512));
        LD_L3_X2(gxv[2], (const unsigned*)(gb_ + 1024));
        asm volatile("s_waitcnt vmcnt(0)" ::: "memory");
      }
      const float r0 =
          1.f / (1.f + __expf(-(__uint_as_float(gxv[0].x) + S0[0])));
      const float z0 =
          1.f / (1.f + __expf(-(__uint_as_float(gxv[1].x) + S0[1])));
      const float a0 = __uint_as_float(gxv[2].x) + r0 * S0[2];
      const float n0 = 1.f - 2.f / (1.f + __expf(2.f * a0));
      const float hn0 = (1.f - z0) * n0 + z0 * hprev0;
      const float r1 =
          1.f / (1.f + __expf(-(__uint_as_float(gxv[0].y) + S1[0])));
      const float z1 =
          1.f / (1.f + __expf(-(__uint_as_float(gxv[1].y) + S1[1])));
      const float a1 = __uint_as_float(gxv[2].y) + r1 * S1[2];
      const float n1 = 1.f - 2.f / (1.f + __expf(2.f * a1));
      const float hn1 = (1.f - z1) * n1 + z1 * hprev1;
      hprev0 = hn0;
      hprev1 = hn1;
      st_l3_u32((unsigned*)(ringW + (size_t)(t + 1) * SLAB + toff),
                packh2t(hn0, hn1));
      if (grp == 1) {
        u32x2 fo;
        fo.x = __float_as_uint(hn0);
        fo.y = __float_as_uint(hn1);
        *(u32x2*)(out + (size_t)t * 32768 + eb * 512 + j) = fo;
      }
    } else {
      // CHECK-LATE guard: cover the prefetched load, then verify/retry
      if (t >= 15) {
        asm volatile("s_waitcnt vmcnt(0)" ::: "memory");
        for (;;) {
          if (__all((guardv & TAG) == TAG)) break;
          __builtin_amdgcn_s_sleep(1);
          LD_L3_U32(guardv, ga);
          asm volatile("s_waitcnt vmcnt(0)" ::: "memory");
        }
      }
      float* gd = gxw + (size_t)(t & 15) * GXSLAB + eb * 1536 + j;
#pragma unroll
      for (int gg = 0; gg < 3; ++gg) {
        u32x2 o;
        o.x = (__float_as_uint(S0[gg]) & ~3u) | gen;
        o.y = (__float_as_uint(S1[gg]) & ~3u) | gen;
        st_l3_u32x2((unsigned*)(gd + gg * 512), o);
      }
    }
    __syncthreads();  // epilogue part-reads done -> next step may overwrite
  }
  asm volatile("s_waitcnt vmcnt(0)" ::: "memory");  // drain final stores
}

extern "C" void kernel_launch(void* const* d_in, const int* in_sizes, int n_in,
                              void* d_out, int out_size, void* d_ws,
                              size_t ws_size, hipStream_t stream) {
  const float* x = (const float*)d_in[0];
  const float* h0 = (const float*)d_in[1];
  const float* w_ih = (const float*)d_in[2];
  const float* w_hh = (const float*)d_in[3];
  const float* b_ih = (const float*)d_in[4];
  const float* b_hh = (const float*)d_in[5];
  float* out = (float*)d_out;
  float* ws = (float*)d_ws;

  gru_init<<<1, 256, 0, stream>>>(ws);

  void* args[] = {(void*)&x,    (void*)&h0,   (void*)&w_ih, (void*)&w_hh,
                  (void*)&b_ih, (void*)&b_hh, (void*)&out,  (void*)&ws};
  (void)hipLaunchCooperativeKernel((const void*)gru_persist, dim3(NWG),
                                   dim3(NTHR), args, 0, stream);
}